// Round 15
// baseline (126.033 us; speedup 1.0000x reference)
//
#include <hip/hip_runtime.h>
#include <math.h>

#define BATCH 16
#define NPX 4096            // 64*64
#define CDIM 128
#define CC 116              // conv channels
#define KTAPS 1044          // 9*116

using u16 = unsigned short;
typedef __attribute__((ext_vector_type(8))) short short8;
typedef __attribute__((ext_vector_type(16))) float f32x16;

__device__ __forceinline__ float swishf(float z) {
    return z / (1.f + __expf(-z));
}
__device__ __forceinline__ float bf2f(u16 u) {
    union { unsigned int i; float f; } v; v.i = ((unsigned int)u) << 16; return v.f;
}
__device__ __forceinline__ u16 f2bf(float f) {
    union { float f; unsigned int i; } v; v.f = f;
    unsigned int r = v.i + 0x7fffu + ((v.i >> 16) & 1u);
    return (u16)(r >> 16);
}

// ---------------- 4-qubit circuit ----------------
__device__ void run_circuit(const float* ang, const float* th, float* z) {
    float ar[16], ai[16];
#pragma unroll
    for (int k = 0; k < 16; ++k) { ar[k] = 0.f; ai[k] = 0.f; }
    ar[0] = 1.f;
#pragma unroll
    for (int pass = 0; pass < 2; ++pass) {
        const float* a = pass ? th : ang;
#pragma unroll
        for (int w = 0; w < 4; ++w) {
            float half = 0.5f * a[w];
            float cth = cosf(half), sth = sinf(half);
            int m = 1 << (3 - w);
#pragma unroll
            for (int k = 0; k < 16; ++k) {
                if (k & m) continue;
                int k2 = k | m;
                float r0 = ar[k], i0 = ai[k], r1 = ar[k2], i1 = ai[k2];
                ar[k]  = cth * r0 + sth * i1;
                ai[k]  = cth * i0 - sth * r1;
                ar[k2] = sth * i0 + cth * r1;
                ai[k2] = -sth * r0 + cth * i1;
            }
        }
    }
#pragma unroll
    for (int e = 0; e < 4; ++e) {
        const int cwi[4] = {0, 1, 2, 3};
        const int twi[4] = {1, 2, 3, 0};
        int mc = 1 << (3 - cwi[e]), mt = 1 << (3 - twi[e]);
#pragma unroll
        for (int k = 0; k < 16; ++k) {
            if ((k & mc) && !(k & mt)) {
                int k2 = k | mt;
                float tr = ar[k]; ar[k] = ar[k2]; ar[k2] = tr;
                float ti = ai[k]; ai[k] = ai[k2]; ai[k2] = ti;
            }
        }
    }
    float zz[4] = {0.f, 0.f, 0.f, 0.f};
#pragma unroll
    for (int k = 0; k < 16; ++k) {
        float p = ar[k] * ar[k] + ai[k] * ai[k];
#pragma unroll
        for (int w = 0; w < 4; ++w) zz[w] += ((k >> (3 - w)) & 1) ? -p : p;
    }
#pragma unroll
    for (int w = 0; w < 4; ++w) z[w] = zz[w];
}

// -------- merged: pooled partials (bx<128) | csum zero (128..143) | time MLP
//          (144..159) | weight-standardize+pack (160..415) --------
__global__ void k_misc(const float* __restrict__ x, float* __restrict__ part,
                       float* __restrict__ csums,
                       const float* __restrict__ te, const float* __restrict__ W,
                       const float* __restrict__ tb, float* __restrict__ t,
                       const float* __restrict__ K0, const float* __restrict__ K1,
                       u16* __restrict__ kqp0, u16* __restrict__ kqp1) {
    const int bx = blockIdx.x, tid = threadIdx.x;
    __shared__ float red[12][256];
    __shared__ float se[512];
    __shared__ float rs[256], rss[256], mb[2];
    if (bx < 128) {
        const int b = bx >> 3, seg = bx & 7;
        float s[12];
#pragma unroll
        for (int c = 0; c < 12; ++c) s[c] = 0.f;
        const float* xb = x + (size_t)(b * 4096 + seg * 512) * CDIM;
#pragma unroll
        for (int i = 0; i < 2; ++i) {
            const float4* p = (const float4*)(xb + (size_t)(tid + i * 256) * CDIM);
            float4 v0 = p[0], v1 = p[1], v2 = p[2];
            s[0] += v0.x; s[1] += v0.y; s[2] += v0.z; s[3] += v0.w;
            s[4] += v1.x; s[5] += v1.y; s[6] += v1.z; s[7] += v1.w;
            s[8] += v2.x; s[9] += v2.y; s[10] += v2.z; s[11] += v2.w;
        }
#pragma unroll
        for (int c = 0; c < 12; ++c) red[c][tid] = s[c];
        __syncthreads();
        for (int st = 128; st > 0; st >>= 1) {
            if (tid < st) {
#pragma unroll
                for (int c = 0; c < 12; ++c) red[c][tid] += red[c][tid + st];
            }
            __syncthreads();
        }
        if (tid < 12) part[bx * 12 + tid] = red[tid][0];
        return;
    }
    if (bx < 144) {
        int i = (bx - 128) * 256 + tid;
        csums[i * 2] = 0.f;
        csums[i * 2 + 1] = 0.f;
        return;
    }
    if (bx < 160) {
        const int b = bx - 144;
        for (int k = tid; k < 512; k += 256) se[k] = swishf(te[b * 512 + k]);
        __syncthreads();
        float acc = tb[tid];
        for (int k = 0; k < 512; ++k) acc += se[k] * W[k * 256 + tid];
        t[b * 256 + tid] = acc;
        return;
    }
    const int r = bx - 160;
    const float* K = (r >> 7) ? K1 : K0;
    u16* kqp = (r >> 7) ? kqp1 : kqp0;
    const int o = r & 127;
    float s = 0.f, ss = 0.f;
    if (o < CC) {
        for (int idx = tid; idx < KTAPS; idx += 256) {
            float v = K[(size_t)idx * CC + o];
            s += v; ss += v * v;
        }
    }
    rs[tid] = s; rss[tid] = ss;
    __syncthreads();
    for (int st = 128; st > 0; st >>= 1) {
        if (tid < st) { rs[tid] += rs[tid + st]; rss[tid] += rss[tid + st]; }
        __syncthreads();
    }
    if (tid == 0) {
        float m = rs[0] * (1.f / KTAPS);
        float var = rss[0] * (1.f / KTAPS) - m * m;
        mb[0] = m;
        mb[1] = rsqrtf(var + 1e-5f);
    }
    __syncthreads();
    float m = mb[0], inv = mb[1];
    for (int idx = tid; idx < 1152; idx += 256) {
        int tap = idx >> 7, ic = idx & 127;
        float v = 0.f;
        if (o < CC && ic < CC) v = (K[((size_t)tap * CC + ic) * CC + o] - m) * inv;
        int step = tap * 8 + (ic >> 4);
        int lane2 = ((ic >> 3) & 1) * 32 + (o & 31);
        int j = ic & 7;
        kqp[(size_t)(step * 4 + (o >> 5)) * 512 + lane2 * 8 + j] = f2bf(v);
    }
}

// ---------------- MFMA 32x32x16 implicit-GEMM conv, 64px x 128oc, 512 threads ----
// 8 waves = 4 ng (oc group of 32) x 2 kg (K half). Wave: 2 M-frags x 1 N x 36 steps.
// LDS 3 rows x 64px x 128ch = 48KB -> 3 blocks/CU (6 waves/SIMD, VGPR cap ~85).
// B-frags read once per block (no duplication); kg partials combined via LDS.
template <int MODE>
__launch_bounds__(512, 3)
__global__ void k_conv(const void* __restrict__ inp, const float* __restrict__ Acoef,
                       const float* __restrict__ Bcoef, const u16* __restrict__ kqp,
                       const float* __restrict__ bias, u16* __restrict__ outp,
                       float* __restrict__ csum) {
    __shared__ u16 As[3 * 64 * 128];   // 48KB stage; epilogue: [0,32KB) f32 comb, [32KB,48KB) u16 repack
    const int hb = blockIdx.x, b = blockIdx.y;
    const int h = ((hb & 7) << 3) | (hb >> 3);   // XCD hb&7 -> rows [8k, 8k+8)
    const int tid = threadIdx.x, lane = tid & 63, wid = tid >> 6;
    const int ng = wid >> 1, kg = wid & 1;
    const int l31 = lane & 31;
    const int pp = tid >> 3, ck8 = tid & 7;      // staging: px, 16-ch chunk
    const int swz = (pp & 15) << 4;

    // MODE1 FiLM coefs in registers (L2-hot, one-time)
    float cfa[16], cfb[16];
    if (MODE == 1) {
        const float* ap = Acoef + b * 128 + 12 + ck8 * 16;
        const float* bp2 = Bcoef + b * 128 + 12 + ck8 * 16;
        const int nj = (ck8 < 7) ? 4 : 1;
#pragma unroll
        for (int j = 0; j < 4; ++j) {
            if (j < nj) {
                *(float4*)&cfa[j * 4] = ((const float4*)ap)[j];
                *(float4*)&cfb[j * 4] = ((const float4*)bp2)[j];
            } else {
#pragma unroll
                for (int e = 0; e < 4; ++e) { cfa[j * 4 + e] = 0.f; cfb[j * 4 + e] = 0.f; }
            }
        }
    }

    float fr0[16], fr1[16], fr2[16];
    short8 s0[2], s1[2], s2[2];
    bool v0r, v1r, v2r;

#define LOADROW(r, fv, sv, val) do { \
    const int hi_ = h + (r) - 1; \
    val = (hi_ >= 0 && hi_ < 64); \
    if (val) { \
        const size_t px_ = (size_t)((b * 64 + hi_) * 64 + pp); \
        if (MODE == 0) { \
            const float* sp_ = (const float*)inp + px_ * 128 + 12 + ck8 * 16; \
            const int nj_ = (ck8 < 7) ? 4 : 1; \
            _Pragma("unroll") for (int j = 0; j < 4; ++j) \
                if (j < nj_) *(float4*)&fv[j * 4] = ((const float4*)sp_)[j]; \
        } else { \
            const u16* sp_ = (const u16*)inp + px_ * 128 + ck8 * 16; \
            sv[0] = ((const short8*)sp_)[0]; \
            sv[1] = ((const short8*)sp_)[1]; \
        } \
    } \
} while (0)

#define CVTWRITE(r, fv, sv, val) do { \
    u16 t_[16]; \
    if (val) { \
        if (MODE == 0) { \
            _Pragma("unroll") for (int e = 0; e < 16; ++e) { \
                int c_ = ck8 * 16 + e; \
                t_[e] = (c_ < CC) ? f2bf(fv[e]) : (u16)0; \
            } \
        } else { \
            _Pragma("unroll") for (int e = 0; e < 16; ++e) { \
                int c_ = ck8 * 16 + e; \
                float f_ = bf2f((u16)sv[e >> 3][e & 7]); \
                float w_ = swishf(f_ * cfa[e] + cfb[e]); \
                t_[e] = (c_ < CC) ? f2bf(w_) : (u16)0; \
            } \
        } \
    } else { \
        _Pragma("unroll") for (int e = 0; e < 16; ++e) t_[e] = 0; \
    } \
    char* rb_ = (char*)As + ((r) * 64 + pp) * 256; \
    *(short8*)(rb_ + ((ck8 * 32) ^ swz)) = *(const short8*)&t_[0]; \
    *(short8*)(rb_ + ((ck8 * 32 + 16) ^ swz)) = *(const short8*)&t_[8]; \
} while (0)

    LOADROW(0, fr0, s0, v0r);
    LOADROW(1, fr1, s1, v1r);
    LOADROW(2, fr2, s2, v2r);
    CVTWRITE(0, fr0, s0, v0r);
    CVTWRITE(1, fr1, s1, v1r);
    CVTWRITE(2, fr2, s2, v2r);

    // A-frag per-lane byte bases (XOR-foldable; ds imm offset carries p*16384)
    const int kh16 = (lane >> 5) << 4;
    int V0[3], V1[3];
#pragma unroll
    for (int q = 0; q < 3; ++q) {
        int c0 = l31 + q - 1;       c0 = c0 < 0 ? 0 : c0;
        int c1 = 32 + l31 + q - 1;  c1 = c1 > 63 ? 63 : c1;
        V0[q] = (c0 << 8) + (kh16 ^ ((c0 & 15) << 4));
        V1[q] = (c1 << 8) + (kh16 ^ ((c1 & 15) << 4));
    }
    const bool e0 = (l31 == 0), e1 = (l31 == 31);
    const short8 zero8 = {0, 0, 0, 0, 0, 0, 0, 0};
    const u16* bp = kqp + (size_t)ng * 512 + (size_t)lane * 8;

    __syncthreads();

    f32x16 acc0, acc1;
#pragma unroll
    for (int r = 0; r < 16; ++r) { acc0[r] = 0.f; acc1[r] = 0.f; }
    short8 afr[2][2], breg[2];

#define AREAD(dst, s) do { \
    const int p_ = ((s) >> 3) / 3; \
    const int q_ = ((s) >> 3) % 3; \
    const int chb_ = ((s) & 7) << 5; \
    dst[0] = *(const short8*)((const char*)As + (p_ * 16384 + (V0[q_] ^ chb_))); \
    dst[1] = *(const short8*)((const char*)As + (p_ * 16384 + (V1[q_] ^ chb_))); \
} while (0)

#define STEP(i, BASE) do { \
    const int s_ = (BASE) + (i); \
    const int cur_ = (i) & 1, nxt_ = cur_ ^ 1; \
    if ((i) + 1 < 36) AREAD(afr[nxt_], s_ + 1); \
    const int q_ = (s_ >> 3) % 3; \
    short8 a0_ = afr[cur_][0], a1_ = afr[cur_][1]; \
    if (q_ == 0) a0_ = e0 ? zero8 : a0_; \
    if (q_ == 2) a1_ = e1 ? zero8 : a1_; \
    __builtin_amdgcn_s_setprio(1); \
    acc0 = __builtin_amdgcn_mfma_f32_32x32x16_bf16(a0_, breg[(i) & 1], acc0, 0, 0, 0); \
    acc1 = __builtin_amdgcn_mfma_f32_32x32x16_bf16(a1_, breg[(i) & 1], acc1, 0, 0, 0); \
    __builtin_amdgcn_s_setprio(0); \
    if ((i) + 2 < 36) breg[(i) & 1] = *(const short8*)(bp + ((size_t)(s_ + 2) << 11)); \
} while (0)

#define RUNPHASE(BASE) do { \
    breg[0] = *(const short8*)(bp + ((size_t)(BASE) << 11)); \
    breg[1] = *(const short8*)(bp + ((size_t)((BASE) + 1) << 11)); \
    AREAD(afr[0], (BASE)); \
    _Pragma("unroll") for (int i = 0; i < 36; ++i) STEP(i, BASE); \
} while (0)

    if (kg == 0) { RUNPHASE(0); } else { RUNPHASE(36); }

    // ---- epilogue: kg-combine via LDS, bias, csum, repack, coalesced store ----
    const int oc = ng * 32 + l31;
    const int rbase = (lane >> 5) << 2;
    __syncthreads();                        // all ds_reads of As done
    {
        float* comb = (float*)As;           // [4 ng][64 px][32 oc] f32 = 32KB
        if (kg == 1) {
#pragma unroll
            for (int r = 0; r < 16; ++r) {
                int row = (r & 3) + ((r >> 2) << 3) + rbase;
                comb[((ng * 64 + row) * 32) + l31] = acc0[r];
                comb[((ng * 64 + 32 + row) * 32) + l31] = acc1[r];
            }
        }
    }
    __syncthreads();
    float cs = 0.f, cq = 0.f;
    if (kg == 0) {
        const float* comb = (const float*)As;
        u16* rep = (u16*)((char*)As + 32768); // [64 px][128 oc] u16 = 16KB
        const float bv = (oc < CC) ? bias[oc] : 0.f;
#pragma unroll
        for (int r = 0; r < 16; ++r) {
            int row = (r & 3) + ((r >> 2) << 3) + rbase;
            float v0f = acc0[r] + comb[((ng * 64 + row) * 32) + l31] + bv;
            float v1f = acc1[r] + comb[((ng * 64 + 32 + row) * 32) + l31] + bv;
            rep[row * 128 + oc] = f2bf(v0f);
            rep[(32 + row) * 128 + oc] = f2bf(v1f);
            cs += v0f + v1f;
            cq += v0f * v0f + v1f * v1f;
        }
    }
    __syncthreads();
    {
        const u16* rep = (const u16*)((char*)As + 32768);
        size_t obase = (size_t)(b * 4096 + h * 64) * 128;
        *(short8*)&outp[obase + tid * 16] = *(const short8*)&rep[tid * 16];
        *(short8*)&outp[obase + tid * 16 + 8] = *(const short8*)&rep[tid * 16 + 8];
    }
    if (kg == 0) {
        cs += __shfl_xor(cs, 32);
        cq += __shfl_xor(cq, 32);
        if (lane < 32) {
            atomicAdd(&csum[(b * 128 + oc) * 2], cs);
            atomicAdd(&csum[(b * 128 + oc) * 2 + 1], cq);
        }
    }
#undef LOADROW
#undef CVTWRITE
#undef AREAD
#undef STEP
#undef RUNPHASE
}

// ---------------- fused: pooled + circuit1 + GN0 stats + FiLM coefs + circuit 2 ----
__global__ void k_mid0(const float* __restrict__ part, const float* __restrict__ csum,
                       const float* __restrict__ t, const float* __restrict__ gs,
                       const float* __restrict__ gb, const float* __restrict__ qp,
                       float* __restrict__ A, float* __restrict__ Bc,
                       float* __restrict__ y2) {
    __shared__ float pooled_s[192], y1s[192], sst[128][2];
    int tid = threadIdx.x;
    if (tid < 192) {
        int b = tid / 12, c = tid % 12;
        float s = 0.f;
#pragma unroll
        for (int k = 0; k < 8; ++k) s += part[(b * 8 + k) * 12 + c];
        pooled_s[tid] = s * (1.f / 4096.f);
    }
    __syncthreads();
    if (tid < 48) {
        int b = tid / 3, g = tid % 3;
        float z[4];
        run_circuit(&pooled_s[b * 12 + g * 4], qp + g * 4, z);
#pragma unroll
        for (int w = 0; w < 4; ++w) y1s[b * 12 + g * 4 + w] = z[w];
    }
    __syncthreads();
    if (tid < 128) {
        int b = tid >> 3, g = tid & 7;
        float S = 0.f, SS = 0.f;
#pragma unroll
        for (int e = 0; e < 16; ++e) {
            int orig = g * 16 + e;
            if (orig >= 12) {
                int cc = orig - 12;
                S += csum[(b * 128 + cc) * 2];
                SS += csum[(b * 128 + cc) * 2 + 1];
            }
        }
        if (g == 0) {
#pragma unroll
            for (int c = 0; c < 12; ++c) {
                float v = y1s[b * 12 + c];
                S += 4096.f * v;
                SS += 4096.f * v * v;
            }
        }
        float mu = S * (1.f / 65536.f);
        float var = SS * (1.f / 65536.f) - mu * mu;
        sst[tid][0] = mu;
        sst[tid][1] = rsqrtf(var + 1e-6f);
    }
    __syncthreads();
    for (int i = tid; i < 2048; i += 256) {
        int b = i >> 7, c = i & 127, g = c >> 4;
        float mu = sst[b * 8 + g][0], isd = sst[b * 8 + g][1];
        float sc = t[b * 256 + c], sh = t[b * 256 + 128 + c];
        float a = isd * gs[c];
        float bb = gb[c] - mu * a;
        A[i] = a * (1.f + sc);
        Bc[i] = bb * (1.f + sc) + sh;
    }
    if (tid < 48) {
        int b = tid / 3, gq = tid % 3;
        float pin[4], z[4];
        float mu = sst[b * 8][0], isd = sst[b * 8][1];
#pragma unroll
        for (int w = 0; w < 4; ++w) {
            int c = gq * 4 + w;
            float a = isd * gs[c];
            float bb = gb[c] - mu * a;
            float sc = t[b * 256 + c], sh = t[b * 256 + 128 + c];
            float v = y1s[b * 12 + c];
            pin[w] = swishf(v * (a * (1.f + sc)) + (bb * (1.f + sc) + sh));
        }
        run_circuit(pin, qp + gq * 4, z);
#pragma unroll
        for (int w = 0; w < 4; ++w) y2[b * 12 + gq * 4 + w] = z[w];
    }
}

// ---------------- fused: GN1 stats + out = x + swish(A2*v + B2) ----------------
__global__ void k_final(const float* __restrict__ x, const u16* __restrict__ co,
                        const float* __restrict__ csum, const float* __restrict__ y2,
                        const float* __restrict__ gs, const float* __restrict__ gb,
                        float* __restrict__ outp) {
    __shared__ float sst[8][2];
    const int t = blockIdx.x, b = blockIdx.y;
    const int seg = t >> 6, hraw = t & 63;
    const int h = ((hraw & 7) << 3) | (hraw >> 3);
    const int tid = threadIdx.x;
    if (tid < 8) {
        const int g = tid;
        float S = 0.f, SS = 0.f;
#pragma unroll
        for (int e = 0; e < 16; ++e) {
            int orig = g * 16 + e;
            if (orig >= 12) {
                int cc = orig - 12;
                S += csum[(b * 128 + cc) * 2];
                SS += csum[(b * 128 + cc) * 2 + 1];
            }
        }
        if (g == 0) {
#pragma unroll
            for (int c = 0; c < 12; ++c) {
                float v = y2[b * 12 + c];
                S += 4096.f * v;
                SS += 4096.f * v * v;
            }
        }
        float mu = S * (1.f / 65536.f);
        float var = SS * (1.f / 65536.f) - mu * mu;
        sst[g][0] = mu;
        sst[g][1] = rsqrtf(var + 1e-6f);
    }
    __syncthreads();
    const size_t px = (size_t)(b * 64 + h) * 64 + seg * 8 + (tid >> 5);
    const int c4 = tid & 31, c = c4 * 4;
    const int g = c >> 4;
    const float mu = sst[g][0], isd = sst[g][1];
    float4 gsv = *(const float4*)(gs + c);
    float4 gbv = *(const float4*)(gb + c);
    float a0 = isd * gsv.x, a1 = isd * gsv.y, a2 = isd * gsv.z, a3 = isd * gsv.w;
    float b0 = gbv.x - mu * a0, b1 = gbv.y - mu * a1;
    float b2 = gbv.z - mu * a2, b3 = gbv.w - mu * a3;
    float4 xv = *(const float4*)(x + px * CDIM + c);
    float4 r;
    if (c4 < 3) {
        const float* q = y2 + b * 12 + c;
        r.x = xv.x + swishf(q[0] * a0 + b0);
        r.y = xv.y + swishf(q[1] * a1 + b1);
        r.z = xv.z + swishf(q[2] * a2 + b2);
        r.w = xv.w + swishf(q[3] * a3 + b3);
    } else {
        const u16* hp = co + px * 128 + (c - 12);
        r.x = xv.x + swishf(bf2f(hp[0]) * a0 + b0);
        r.y = xv.y + swishf(bf2f(hp[1]) * a1 + b1);
        r.z = xv.z + swishf(bf2f(hp[2]) * a2 + b2);
        r.w = xv.w + swishf(bf2f(hp[3]) * a3 + b3);
    }
    *(float4*)(outp + px * CDIM + c) = r;
}

extern "C" void kernel_launch(void* const* d_in, const int* in_sizes, int n_in,
                              void* d_out, int out_size, void* d_ws, size_t ws_size,
                              hipStream_t stream) {
    const float* x        = (const float*)d_in[0];
    const float* time_emb = (const float*)d_in[1];
    const float* qparams  = (const float*)d_in[2];
    const float* c0k      = (const float*)d_in[3];
    const float* c0b      = (const float*)d_in[4];
    const float* c1k      = (const float*)d_in[5];
    const float* c1b      = (const float*)d_in[6];
    const float* g0s      = (const float*)d_in[7];
    const float* g0b      = (const float*)d_in[8];
    const float* g1s      = (const float*)d_in[9];
    const float* g1b      = (const float*)d_in[10];
    const float* tw       = (const float*)d_in[11];
    const float* tb       = (const float*)d_in[12];
    float* outp = (float*)d_out;
    float* ws = (float*)d_ws;

    size_t o = 0;
    auto alloc = [&](size_t n) { size_t r = o; o += (n + 15) & ~(size_t)15; return r; };
    float* part   = ws + alloc(1536);
    float* csums  = ws + alloc(8192);            // csum0 | csum1
    float* csum0  = csums;
    float* csum1  = csums + 4096;
    float* t      = ws + alloc(4096);
    float* A      = ws + alloc(2048);
    float* Bc     = ws + alloc(2048);
    float* y2     = ws + alloc(192);
    u16* kqp0     = (u16*)(ws + alloc(73728));   // 72*4*512 bf16
    u16* kqp1     = (u16*)(ws + alloc(73728));
    u16* convA    = (u16*)(ws + alloc(4194304)); // [16][4096][128] bf16 (conv0 out)
    u16* convB    = (u16*)(ws + alloc(4194304)); // conv1 out

    k_misc<<<416, 256, 0, stream>>>(x, part, csums, time_emb, tw, tb, t,
                                    c0k, c1k, kqp0, kqp1);

    dim3 cgrid(64, 16);
    k_conv<0><<<cgrid, 512, 0, stream>>>(x, nullptr, nullptr, kqp0, c0b, convA, csum0);
    k_mid0<<<1, 256, 0, stream>>>(part, csum0, t, g0s, g0b, qparams, A, Bc, y2);

    k_conv<1><<<cgrid, 512, 0, stream>>>(convA, A, Bc, kqp1, c1b, convB, csum1);
    k_final<<<dim3(512, 16), 256, 0, stream>>>(x, convB, csum1, y2, g1s, g1b, outp);
}